// Round 6
// baseline (711.045 us; speedup 1.0000x reference)
//
#include <hip/hip_runtime.h>
#include <hip/hip_bf16.h>

// EdgewiseReduce: out[n, :] = sum_{e : dst[e]==n} edge_data[e, :] * 0.5
// E = 1.6M, D = 32, N = 100K.
//
// History:
//  R1: 51.2M f32 global atomics -> 819 MB of 16B txns, 647 us (atomic-bound).
//  R2: counting sort; random 4B scatter -> 106 MB line writebacks, 494 us.
//  R3: replicated scan -> 1.6 GB L3 traffic, latency-bound, 378 us.
//  R4: bucket sort + gather, 2-deep chain: 352 GB/s, 340 us (latency-bound).
//  R5: "8-deep" gather compiled to 1-deep (VGPR=32 proves loads were
//      interleaved with atomics); same 374 us. Order scatter still sub-line.
// R6: (a) gather batch made un-killable: unconditional straight-line loads,
//     tail clamped to row 0 + dummy LDS acc row (cndmask, no branches),
//     sched_barrier(0) pins all 8 loads before the atomic block.
//     (b) scatter uses 128 blocks so each (block,bucket) order region is
//     ~128 B -> full-line write combining in L2.

#define D 32
#define FACTOR 0.5f
#define BSHIFT 7                 // 128 nodes per bucket
#define BNODES (1 << BSHIFT)
#define ASTRIDE 33               // LDS acc row stride (bank decorrelation)

// ---------- K1: global bucket histogram (int4 loads) ----------
__global__ void hist_kernel(const int* __restrict__ dst, int* __restrict__ ghist,
                            int E, int N, int nb) {
  extern __shared__ int lhist[];
  for (int i = threadIdx.x; i < nb; i += blockDim.x) lhist[i] = 0;
  __syncthreads();
  const int4* dst4 = (const int4*)dst;
  int E4 = E >> 2;
  for (int i = blockIdx.x * blockDim.x + threadIdx.x; i < E4;
       i += gridDim.x * blockDim.x) {
    int4 v = dst4[i];
    if ((unsigned)v.x < (unsigned)N) atomicAdd(&lhist[v.x >> BSHIFT], 1);
    if ((unsigned)v.y < (unsigned)N) atomicAdd(&lhist[v.y >> BSHIFT], 1);
    if ((unsigned)v.z < (unsigned)N) atomicAdd(&lhist[v.z >> BSHIFT], 1);
    if ((unsigned)v.w < (unsigned)N) atomicAdd(&lhist[v.w >> BSHIFT], 1);
  }
  int t = (E4 << 2) + blockIdx.x * blockDim.x + threadIdx.x;
  if (t < E) {
    int d = dst[t];
    if ((unsigned)d < (unsigned)N) atomicAdd(&lhist[d >> BSHIFT], 1);
  }
  __syncthreads();
  for (int i = threadIdx.x; i < nb; i += blockDim.x)
    if (lhist[i]) atomicAdd(&ghist[i], lhist[i]);
}

// ---------- K2: exclusive scan over nb (<=1024) buckets, one block ----------
__global__ void scan_kernel(const int* __restrict__ ghist, int* __restrict__ bases,
                            int* __restrict__ cursor, int nb) {
  __shared__ int buf[1024];
  int x = threadIdx.x;
  int v = (x < nb) ? ghist[x] : 0;
  buf[x] = v;
  __syncthreads();
  for (int off = 1; off < 1024; off <<= 1) {
    int t = (x >= off) ? buf[x - off] : 0;
    __syncthreads();
    buf[x] += t;
    __syncthreads();
  }
  if (x < nb) {
    int b = buf[x] - v;
    bases[x] = b;
    cursor[x] = b;
  }
}

// ---------- K3: per-block reserve + scatter packed ids (128 blocks) ----------
__global__ void scatter_kernel(const int* __restrict__ dst, int* __restrict__ gcursor,
                               int* __restrict__ order, int E, int N, int nb,
                               int chunk) {
  extern __shared__ int sm[];
  int* lhist = sm;            // [nb]
  int* lcur = sm + nb;        // [nb]
  int lo = blockIdx.x * chunk;          // chunk is 4-aligned
  int hiE = min(lo + chunk, E);
  const int4* dst4 = (const int4*)dst;

  for (int i = threadIdx.x; i < nb; i += blockDim.x) lhist[i] = 0;
  __syncthreads();

  int lo4 = lo >> 2;
  int full4 = (hiE - lo) >> 2;
  for (int i = threadIdx.x; i < full4; i += blockDim.x) {
    int4 v = dst4[lo4 + i];
    if ((unsigned)v.x < (unsigned)N) atomicAdd(&lhist[v.x >> BSHIFT], 1);
    if ((unsigned)v.y < (unsigned)N) atomicAdd(&lhist[v.y >> BSHIFT], 1);
    if ((unsigned)v.z < (unsigned)N) atomicAdd(&lhist[v.z >> BSHIFT], 1);
    if ((unsigned)v.w < (unsigned)N) atomicAdd(&lhist[v.w >> BSHIFT], 1);
  }
  int tb = lo + (full4 << 2) + threadIdx.x;
  if (tb < hiE) {
    int d = dst[tb];
    if ((unsigned)d < (unsigned)N) atomicAdd(&lhist[d >> BSHIFT], 1);
  }
  __syncthreads();

  for (int i = threadIdx.x; i < nb; i += blockDim.x) {
    int c = lhist[i];
    lcur[i] = c ? atomicAdd(&gcursor[i], c) : 0;
  }
  __syncthreads();

  for (int i = threadIdx.x; i < full4; i += blockDim.x) {
    int e = lo + (i << 2);
    int4 v = dst4[lo4 + i];
    if ((unsigned)v.x < (unsigned)N)
      order[atomicAdd(&lcur[v.x >> BSHIFT], 1)] = ((e + 0) << BSHIFT) | (v.x & (BNODES - 1));
    if ((unsigned)v.y < (unsigned)N)
      order[atomicAdd(&lcur[v.y >> BSHIFT], 1)] = ((e + 1) << BSHIFT) | (v.y & (BNODES - 1));
    if ((unsigned)v.z < (unsigned)N)
      order[atomicAdd(&lcur[v.z >> BSHIFT], 1)] = ((e + 2) << BSHIFT) | (v.z & (BNODES - 1));
    if ((unsigned)v.w < (unsigned)N)
      order[atomicAdd(&lcur[v.w >> BSHIFT], 1)] = ((e + 3) << BSHIFT) | (v.w & (BNODES - 1));
  }
  if (tb < hiE) {
    int d = dst[tb];
    if ((unsigned)d < (unsigned)N)
      order[atomicAdd(&lcur[d >> BSHIFT], 1)] = (tb << BSHIFT) | (d & (BNODES - 1));
  }
}

// ---------- K4: gather-reduce per bucket, straight-line 8-deep batches ----
#define K4_THREADS 512
#define STAGE 1024
__global__ __launch_bounds__(K4_THREADS)
void gather_kernel(const float4* __restrict__ data, const int* __restrict__ order,
                   const int* __restrict__ bases, const int* __restrict__ ghist,
                   float4* __restrict__ out, int N) {
  __shared__ float acc[(BNODES + 1) * ASTRIDE];  // +1 dummy row for tail lanes
  __shared__ int stage[STAGE];
  int b = blockIdx.x;
  int base = bases[b];
  int count = ghist[b];
  int lo = b << BSHIFT;

  for (int i = threadIdx.x; i < (BNODES + 1) * ASTRIDE; i += K4_THREADS)
    acc[i] = 0.f;

  const int q = threadIdx.x & 7;       // float4 slot within row
  const int g = threadIdx.x >> 3;      // group 0..63

  for (int c0 = 0; c0 < count; c0 += STAGE) {
    int csz = min(STAGE, count - c0);
    __syncthreads();                    // stage reusable
    for (int i = threadIdx.x; i < csz; i += K4_THREADS)
      stage[i] = order[base + c0 + i];
    __syncthreads();

    #pragma unroll
    for (int k0 = 0; k0 < STAGE / 64; k0 += 8) {
      int row[8], node[8];
      #pragma unroll
      for (int u = 0; u < 8; ++u) {
        int j = g + 64 * (k0 + u);
        bool ok = j < csz;
        int pk = ok ? stage[j] : 0;     // ds_read executes; result cndmask'd
        row[u] = pk >> BSHIFT;          // row 0 when !ok (valid address)
        node[u] = ok ? (pk & (BNODES - 1)) : BNODES;  // dummy acc row
      }
      float4 v[8];
      #pragma unroll
      for (int u = 0; u < 8; ++u)
        v[u] = data[(size_t)row[u] * 8 + q];   // 8 unconditional loads
      __builtin_amdgcn_sched_barrier(0);        // loads may not sink below
      #pragma unroll
      for (int u = 0; u < 8; ++u) {
        float* a = &acc[node[u] * ASTRIDE + q * 4];
        atomicAdd(a + 0, v[u].x);
        atomicAdd(a + 1, v[u].y);
        atomicAdd(a + 2, v[u].z);
        atomicAdd(a + 3, v[u].w);
      }
    }
  }
  __syncthreads();

  int nlocal = min(BNODES, N - lo);
  for (int t = threadIdx.x; t < nlocal * 8; t += K4_THREADS) {
    int r = t >> 3, jq = t & 7;
    const float* a = &acc[r * ASTRIDE + jq * 4];
    float4 v;
    v.x = a[0] * FACTOR; v.y = a[1] * FACTOR;
    v.z = a[2] * FACTOR; v.w = a[3] * FACTOR;
    out[(size_t)(lo + r) * 8 + jq] = v;
  }
}

// ---------- Fallback: round-1 atomic scatter ----------
__global__ void atomic_kernel(const float4* __restrict__ edge_data,
                              const int* __restrict__ edge_dst,
                              float* __restrict__ out, int E, int N) {
  int tid = blockIdx.x * blockDim.x + threadIdx.x;
  int e = tid >> 3;
  int q = tid & 7;
  if (e >= E) return;
  int dst = edge_dst[e];
  if (dst < 0 || dst >= N) return;
  float4 v = edge_data[(size_t)e * 8 + q];
  float* p = out + (size_t)dst * D + q * 4;
  unsafeAtomicAdd(p + 0, v.x * FACTOR);
  unsafeAtomicAdd(p + 1, v.y * FACTOR);
  unsafeAtomicAdd(p + 2, v.z * FACTOR);
  unsafeAtomicAdd(p + 3, v.w * FACTOR);
}

extern "C" void kernel_launch(void* const* d_in, const int* in_sizes, int n_in,
                              void* d_out, int out_size, void* d_ws, size_t ws_size,
                              hipStream_t stream) {
  const float4* edge_data = (const float4*)d_in[0];
  const int* edge_dst = (const int*)d_in[1];

  int E = in_sizes[1];
  int N = out_size / D;

  int nb = (N + BNODES - 1) >> BSHIFT;            // 782 for N=100K
  size_t need = ((size_t)3 * nb + (size_t)E) * sizeof(int);
  bool pack_ok = ((long long)E << BSHIFT) < (1ll << 31);

  if (nb > 1024 || ws_size < need || !pack_ok) {
    float* out = (float*)d_out;
    hipMemsetAsync(d_out, 0, (size_t)out_size * sizeof(float), stream);
    int total = E * 8;
    atomic_kernel<<<(total + 255) / 256, 256, 0, stream>>>(edge_data, edge_dst, out, E, N);
    return;
  }

  int* ws = (int*)d_ws;
  int* ghist  = ws;                // [nb]
  int* bases  = ws + nb;           // [nb]
  int* cursor = ws + 2 * nb;       // [nb]
  int* order  = ws + 3 * nb;       // [E]

  hipMemsetAsync(ghist, 0, (size_t)nb * sizeof(int), stream);

  size_t lds1 = (size_t)nb * sizeof(int);
  hist_kernel<<<512, 256, lds1, stream>>>(edge_dst, ghist, E, N, nb);

  scan_kernel<<<1, 1024, 0, stream>>>(ghist, bases, cursor, nb);

  // 128 scatter blocks: per-(block,bucket) order region ~E/(128*nb)*4B ~ 64B
  // -> full-line L2 write combining (R2/R5 used 256+ blocks -> 32B regions).
  int nblk3 = 128;
  int chunk = ((E + nblk3 - 1) / nblk3 + 3) & ~3;
  size_t lds3 = (size_t)2 * nb * sizeof(int);
  scatter_kernel<<<nblk3, 256, lds3, stream>>>(edge_dst, cursor, order, E, N, nb, chunk);

  gather_kernel<<<nb, K4_THREADS, 0, stream>>>(
      edge_data, order, bases, ghist, (float4*)d_out, N);
}

// Round 7
// 352.483 us; speedup vs baseline: 2.0172x; 2.0172x over previous
//
#include <hip/hip_runtime.h>
#include <hip/hip_bf16.h>

// EdgewiseReduce: out[n, :] = sum_{e : dst[e]==n} edge_data[e, :] * 0.5
// E = 1.6M, D = 32, N = 100K.
//
// History:
//  R1: 51.2M f32 global atomics -> 819 MB of 16B txns, 647 us (atomic-bound).
//  R2: counting sort; random 4B scatter -> 106 MB line writebacks, 494 us.
//      BUT its gather (register accumulation) was <130 us — remember this.
//  R3: replicated scan -> 1.6 GB L3 traffic, latency-bound, 378 us.
//  R4-R6: bucket sort fine; gather with LDS-atomic consumption stuck at
//      340-464 us, VGPR pinned at 32 across three restructurings: the
//      compiler will NOT keep global loads in flight across LDS atomics.
// R7: gather consumes into REGISTERS. Per bucket: stage 2048 ids in LDS,
//     in-LDS counting sort by node (128 counters), then each 4-lane group
//     owns ONE node and walks its contiguous sublist with 4-id-unrolled
//     float4 loads (8 loads in flight) into 2 float4 register accumulators;
//     writes out directly. No LDS accumulator, no dummy rows.
//     Scatter uses 64 blocks -> 128 B per-(block,bucket) regions (full line).

#define D 32
#define FACTOR 0.5f
#define BSHIFT 7                 // 128 nodes per bucket
#define BNODES (1 << BSHIFT)

// ---------- K1: global bucket histogram (int4 loads) ----------
__global__ void hist_kernel(const int* __restrict__ dst, int* __restrict__ ghist,
                            int E, int N, int nb) {
  extern __shared__ int lhist[];
  for (int i = threadIdx.x; i < nb; i += blockDim.x) lhist[i] = 0;
  __syncthreads();
  const int4* dst4 = (const int4*)dst;
  int E4 = E >> 2;
  for (int i = blockIdx.x * blockDim.x + threadIdx.x; i < E4;
       i += gridDim.x * blockDim.x) {
    int4 v = dst4[i];
    if ((unsigned)v.x < (unsigned)N) atomicAdd(&lhist[v.x >> BSHIFT], 1);
    if ((unsigned)v.y < (unsigned)N) atomicAdd(&lhist[v.y >> BSHIFT], 1);
    if ((unsigned)v.z < (unsigned)N) atomicAdd(&lhist[v.z >> BSHIFT], 1);
    if ((unsigned)v.w < (unsigned)N) atomicAdd(&lhist[v.w >> BSHIFT], 1);
  }
  int t = (E4 << 2) + blockIdx.x * blockDim.x + threadIdx.x;
  if (t < E) {
    int d = dst[t];
    if ((unsigned)d < (unsigned)N) atomicAdd(&lhist[d >> BSHIFT], 1);
  }
  __syncthreads();
  for (int i = threadIdx.x; i < nb; i += blockDim.x)
    if (lhist[i]) atomicAdd(&ghist[i], lhist[i]);
}

// ---------- K2: exclusive scan over nb (<=1024) buckets, one block ----------
__global__ void scan_kernel(const int* __restrict__ ghist, int* __restrict__ bases,
                            int* __restrict__ cursor, int nb) {
  __shared__ int buf[1024];
  int x = threadIdx.x;
  int v = (x < nb) ? ghist[x] : 0;
  buf[x] = v;
  __syncthreads();
  for (int off = 1; off < 1024; off <<= 1) {
    int t = (x >= off) ? buf[x - off] : 0;
    __syncthreads();
    buf[x] += t;
    __syncthreads();
  }
  if (x < nb) {
    int b = buf[x] - v;
    bases[x] = b;
    cursor[x] = b;
  }
}

// ---------- K3: per-block reserve + scatter packed ids (64 blocks) ----------
__global__ void scatter_kernel(const int* __restrict__ dst, int* __restrict__ gcursor,
                               int* __restrict__ order, int E, int N, int nb,
                               int chunk) {
  extern __shared__ int sm[];
  int* lhist = sm;            // [nb]
  int* lcur = sm + nb;        // [nb]
  int lo = blockIdx.x * chunk;          // chunk is 4-aligned
  int hiE = min(lo + chunk, E);
  const int4* dst4 = (const int4*)dst;

  for (int i = threadIdx.x; i < nb; i += blockDim.x) lhist[i] = 0;
  __syncthreads();

  int lo4 = lo >> 2;
  int full4 = (hiE - lo) >> 2;
  for (int i = threadIdx.x; i < full4; i += blockDim.x) {
    int4 v = dst4[lo4 + i];
    if ((unsigned)v.x < (unsigned)N) atomicAdd(&lhist[v.x >> BSHIFT], 1);
    if ((unsigned)v.y < (unsigned)N) atomicAdd(&lhist[v.y >> BSHIFT], 1);
    if ((unsigned)v.z < (unsigned)N) atomicAdd(&lhist[v.z >> BSHIFT], 1);
    if ((unsigned)v.w < (unsigned)N) atomicAdd(&lhist[v.w >> BSHIFT], 1);
  }
  int tb = lo + (full4 << 2) + threadIdx.x;
  if (tb < hiE) {
    int d = dst[tb];
    if ((unsigned)d < (unsigned)N) atomicAdd(&lhist[d >> BSHIFT], 1);
  }
  __syncthreads();

  for (int i = threadIdx.x; i < nb; i += blockDim.x) {
    int c = lhist[i];
    lcur[i] = c ? atomicAdd(&gcursor[i], c) : 0;
  }
  __syncthreads();

  for (int i = threadIdx.x; i < full4; i += blockDim.x) {
    int e = lo + (i << 2);
    int4 v = dst4[lo4 + i];
    if ((unsigned)v.x < (unsigned)N)
      order[atomicAdd(&lcur[v.x >> BSHIFT], 1)] = ((e + 0) << BSHIFT) | (v.x & (BNODES - 1));
    if ((unsigned)v.y < (unsigned)N)
      order[atomicAdd(&lcur[v.y >> BSHIFT], 1)] = ((e + 1) << BSHIFT) | (v.y & (BNODES - 1));
    if ((unsigned)v.z < (unsigned)N)
      order[atomicAdd(&lcur[v.z >> BSHIFT], 1)] = ((e + 2) << BSHIFT) | (v.z & (BNODES - 1));
    if ((unsigned)v.w < (unsigned)N)
      order[atomicAdd(&lcur[v.w >> BSHIFT], 1)] = ((e + 3) << BSHIFT) | (v.w & (BNODES - 1));
  }
  if (tb < hiE) {
    int d = dst[tb];
    if ((unsigned)d < (unsigned)N)
      order[atomicAdd(&lcur[d >> BSHIFT], 1)] = (tb << BSHIFT) | (d & (BNODES - 1));
  }
}

// ---------- K4: gather-reduce, register accumulation ----------
// 512 threads = 128 groups x 4 lanes; group g owns node (bucket*128 + g).
// Each lane accumulates a 32B slice (2 float4) of its node's row sum.
#define K4_THREADS 512
#define CHUNK 2048
__global__ __launch_bounds__(K4_THREADS)
void gather_kernel(const float4* __restrict__ data, const int* __restrict__ order,
                   const int* __restrict__ bases, const int* __restrict__ ghist,
                   float4* __restrict__ out, int N) {
  __shared__ int ids[CHUNK];       // staged raw chunk
  __shared__ int sorted[CHUNK];    // node-sorted chunk
  __shared__ int hist[BNODES];
  __shared__ int offs[BNODES];
  __shared__ int cur[BNODES];

  const int b = blockIdx.x;
  const int base = bases[b];
  const int count = ghist[b];
  const int lo = b << BSHIFT;
  const int tid = threadIdx.x;
  const int grp = tid >> 2;        // node-within-bucket this group owns
  const int ln = tid & 3;          // 32B slice within the 128B row

  float4 acc0 = make_float4(0.f, 0.f, 0.f, 0.f);
  float4 acc1 = make_float4(0.f, 0.f, 0.f, 0.f);

  for (int c0 = 0; c0 < count; c0 += CHUNK) {
    int csz = min(CHUNK, count - c0);
    __syncthreads();                       // prev consume done
    for (int i = tid; i < BNODES; i += K4_THREADS) hist[i] = 0;
    __syncthreads();
    for (int i = tid; i < csz; i += K4_THREADS) {
      int v = order[base + c0 + i];
      ids[i] = v;
      atomicAdd(&hist[v & (BNODES - 1)], 1);
    }
    __syncthreads();
    if (tid < BNODES) offs[tid] = hist[tid];
    __syncthreads();
    for (int off = 1; off < BNODES; off <<= 1) {   // inclusive scan
      int t = (tid < BNODES && tid >= off) ? offs[tid - off] : 0;
      __syncthreads();
      if (tid < BNODES) offs[tid] += t;
      __syncthreads();
    }
    if (tid < BNODES) cur[tid] = offs[tid] - hist[tid];
    __syncthreads();
    for (int i = tid; i < csz; i += K4_THREADS) {
      int v = ids[i];
      sorted[atomicAdd(&cur[v & (BNODES - 1)], 1)] = v;
    }
    __syncthreads();

    // Consume: this group's contiguous sublist, 4-id unroll (8 loads live).
    int e_ = offs[grp];
    int i = e_ - hist[grp];
    for (; i + 3 < e_; i += 4) {
      int r0 = sorted[i] >> BSHIFT;
      int r1 = sorted[i + 1] >> BSHIFT;
      int r2 = sorted[i + 2] >> BSHIFT;
      int r3 = sorted[i + 3] >> BSHIFT;
      const float4* p0 = data + (size_t)r0 * 8 + ln * 2;
      const float4* p1 = data + (size_t)r1 * 8 + ln * 2;
      const float4* p2 = data + (size_t)r2 * 8 + ln * 2;
      const float4* p3 = data + (size_t)r3 * 8 + ln * 2;
      float4 x0 = p0[0], y0 = p0[1];
      float4 x1 = p1[0], y1 = p1[1];
      float4 x2 = p2[0], y2 = p2[1];
      float4 x3 = p3[0], y3 = p3[1];
      acc0.x += x0.x + x1.x + x2.x + x3.x;
      acc0.y += x0.y + x1.y + x2.y + x3.y;
      acc0.z += x0.z + x1.z + x2.z + x3.z;
      acc0.w += x0.w + x1.w + x2.w + x3.w;
      acc1.x += y0.x + y1.x + y2.x + y3.x;
      acc1.y += y0.y + y1.y + y2.y + y3.y;
      acc1.z += y0.z + y1.z + y2.z + y3.z;
      acc1.w += y0.w + y1.w + y2.w + y3.w;
    }
    for (; i < e_; ++i) {
      int r0 = sorted[i] >> BSHIFT;
      const float4* p0 = data + (size_t)r0 * 8 + ln * 2;
      float4 x0 = p0[0], y0 = p0[1];
      acc0.x += x0.x; acc0.y += x0.y; acc0.z += x0.z; acc0.w += x0.w;
      acc1.x += y0.x; acc1.y += y0.y; acc1.z += y0.z; acc1.w += y0.w;
    }
  }

  int node = lo + grp;
  if (node < N) {
    float4 o0, o1;
    o0.x = acc0.x * FACTOR; o0.y = acc0.y * FACTOR;
    o0.z = acc0.z * FACTOR; o0.w = acc0.w * FACTOR;
    o1.x = acc1.x * FACTOR; o1.y = acc1.y * FACTOR;
    o1.z = acc1.z * FACTOR; o1.w = acc1.w * FACTOR;
    out[(size_t)node * 8 + ln * 2] = o0;
    out[(size_t)node * 8 + ln * 2 + 1] = o1;
  }
}

// ---------- Fallback: round-1 atomic scatter ----------
__global__ void atomic_kernel(const float4* __restrict__ edge_data,
                              const int* __restrict__ edge_dst,
                              float* __restrict__ out, int E, int N) {
  int tid = blockIdx.x * blockDim.x + threadIdx.x;
  int e = tid >> 3;
  int q = tid & 7;
  if (e >= E) return;
  int dst = edge_dst[e];
  if (dst < 0 || dst >= N) return;
  float4 v = edge_data[(size_t)e * 8 + q];
  float* p = out + (size_t)dst * D + q * 4;
  unsafeAtomicAdd(p + 0, v.x * FACTOR);
  unsafeAtomicAdd(p + 1, v.y * FACTOR);
  unsafeAtomicAdd(p + 2, v.z * FACTOR);
  unsafeAtomicAdd(p + 3, v.w * FACTOR);
}

extern "C" void kernel_launch(void* const* d_in, const int* in_sizes, int n_in,
                              void* d_out, int out_size, void* d_ws, size_t ws_size,
                              hipStream_t stream) {
  const float4* edge_data = (const float4*)d_in[0];
  const int* edge_dst = (const int*)d_in[1];

  int E = in_sizes[1];
  int N = out_size / D;

  int nb = (N + BNODES - 1) >> BSHIFT;            // 782 for N=100K
  size_t need = ((size_t)3 * nb + (size_t)E) * sizeof(int);
  bool pack_ok = ((long long)E << BSHIFT) < (1ll << 31);

  if (nb > 1024 || ws_size < need || !pack_ok) {
    float* out = (float*)d_out;
    hipMemsetAsync(d_out, 0, (size_t)out_size * sizeof(float), stream);
    int total = E * 8;
    atomic_kernel<<<(total + 255) / 256, 256, 0, stream>>>(edge_data, edge_dst, out, E, N);
    return;
  }

  int* ws = (int*)d_ws;
  int* ghist  = ws;                // [nb]
  int* bases  = ws + nb;           // [nb]
  int* cursor = ws + 2 * nb;       // [nb]
  int* order  = ws + 3 * nb;       // [E]

  hipMemsetAsync(ghist, 0, (size_t)nb * sizeof(int), stream);

  size_t lds1 = (size_t)nb * sizeof(int);
  hist_kernel<<<512, 256, lds1, stream>>>(edge_dst, ghist, E, N, nb);

  scan_kernel<<<1, 1024, 0, stream>>>(ghist, bases, cursor, nb);

  // 64 scatter blocks: per-(block,bucket) order region ~ E/(64*nb)*4B ~128 B
  // = one full cache line -> clean write combining in L2.
  int nblk3 = 64;
  int chunk = ((E + nblk3 - 1) / nblk3 + 3) & ~3;
  size_t lds3 = (size_t)2 * nb * sizeof(int);
  scatter_kernel<<<nblk3, 256, lds3, stream>>>(edge_dst, cursor, order, E, N, nb, chunk);

  gather_kernel<<<nb, K4_THREADS, 0, stream>>>(
      edge_data, order, bases, ghist, (float4*)d_out, N);
}

// Round 8
// 327.642 us; speedup vs baseline: 2.1702x; 1.0758x over previous
//
#include <hip/hip_runtime.h>
#include <hip/hip_bf16.h>

// EdgewiseReduce: out[n, :] = sum_{e : dst[e]==n} edge_data[e, :] * 0.5
// E = 1.6M, D = 32, N = 100K.
//
// History:
//  R1: 51.2M f32 global atomics -> 819 MB of 16B txns, 647 us.
//  R2: full counting sort; random 4B scatter -> 106 MB line writebacks, 494.
//  R3: replicated scan -> 1.6 GB L3 traffic, 378 us.
//  R4-R6: LDS-atomic gather stuck 340-464 us (compiler won't pipeline
//         global loads across LDS atomics; VGPR pinned at 32).
//  R7: register-accumulating gather + in-LDS bucket sort -> 352 us total.
// R8: fixed-capacity buckets (cap=4096/bucket in the huge ws) remove the
//     hist+scan kernels and one full dst read; scatter reserves via LDS
//     hist against cursors pre-set to b*cap; overflow spills to a list
//     replayed by an atomic kernel (empty in practice). Gather is single
//     chunk per bucket with a 1-wave shfl scan (2 barriers, not 14).

#define D 32
#define FACTOR 0.5f
#define BSHIFT 7                 // 128 nodes per bucket
#define BNODES (1 << BSHIFT)
#define CAPSHIFT 12              // 4096 slots per bucket
#define CAP (1 << CAPSHIFT)

// ---------- K0: init cursors + overflow count ----------
__global__ void init_kernel(int* __restrict__ cursor, int* __restrict__ ovf_count,
                            int nb) {
  int i = blockIdx.x * blockDim.x + threadIdx.x;
  if (i == 0) *ovf_count = 0;
  if (i < nb) cursor[i] = i << CAPSHIFT;
}

// ---------- K1: per-block reserve + scatter packed ids (128 blocks) ----------
__global__ void scatter_kernel(const int* __restrict__ dst, int* __restrict__ gcursor,
                               int* __restrict__ order, int2* __restrict__ ovf,
                               int* __restrict__ ovf_count, int E, int N, int nb,
                               int chunk) {
  extern __shared__ int sm[];
  int* lhist = sm;            // [nb]
  int* lcur = sm + nb;        // [nb]
  int lo = blockIdx.x * chunk;          // chunk is 4-aligned
  int hiE = min(lo + chunk, E);
  const int4* dst4 = (const int4*)dst;

  for (int i = threadIdx.x; i < nb; i += blockDim.x) lhist[i] = 0;
  __syncthreads();

  int lo4 = lo >> 2;
  int full4 = (hiE - lo) >> 2;
  for (int i = threadIdx.x; i < full4; i += blockDim.x) {
    int4 v = dst4[lo4 + i];
    if ((unsigned)v.x < (unsigned)N) atomicAdd(&lhist[v.x >> BSHIFT], 1);
    if ((unsigned)v.y < (unsigned)N) atomicAdd(&lhist[v.y >> BSHIFT], 1);
    if ((unsigned)v.z < (unsigned)N) atomicAdd(&lhist[v.z >> BSHIFT], 1);
    if ((unsigned)v.w < (unsigned)N) atomicAdd(&lhist[v.w >> BSHIFT], 1);
  }
  int tb = lo + (full4 << 2) + threadIdx.x;
  if (tb < hiE) {
    int d = dst[tb];
    if ((unsigned)d < (unsigned)N) atomicAdd(&lhist[d >> BSHIFT], 1);
  }
  __syncthreads();

  for (int i = threadIdx.x; i < nb; i += blockDim.x) {
    int c = lhist[i];
    lcur[i] = c ? atomicAdd(&gcursor[i], c) : 0;   // global positions
  }
  __syncthreads();

  #define EMIT(dd, ee)                                                        \
    if ((unsigned)(dd) < (unsigned)N) {                                       \
      int bkt = (dd) >> BSHIFT;                                               \
      int pos = atomicAdd(&lcur[bkt], 1);                                     \
      if (pos < ((bkt + 1) << CAPSHIFT)) {                                    \
        order[pos] = ((ee) << BSHIFT) | ((dd) & (BNODES - 1));                \
      } else {                                                                \
        int op = atomicAdd(ovf_count, 1);                                     \
        ovf[op] = make_int2((ee), (dd));                                      \
      }                                                                       \
    }

  for (int i = threadIdx.x; i < full4; i += blockDim.x) {
    int e = lo + (i << 2);
    int4 v = dst4[lo4 + i];
    EMIT(v.x, e + 0)
    EMIT(v.y, e + 1)
    EMIT(v.z, e + 2)
    EMIT(v.w, e + 3)
  }
  if (tb < hiE) {
    int d = dst[tb];
    EMIT(d, tb)
  }
  #undef EMIT
}

// ---------- K2: gather-reduce, register accumulation, 1-wave scan ----------
// 512 threads = 128 groups x 4 lanes; group g owns node (bucket*128 + g).
#define K4_THREADS 512
__global__ __launch_bounds__(K4_THREADS)
void gather_kernel(const float4* __restrict__ data, const int* __restrict__ order,
                   const int* __restrict__ cursor, float4* __restrict__ out,
                   int N) {
  __shared__ int ids[CAP];         // staged bucket ids (16 KB)
  __shared__ int sorted[CAP];      // node-sorted ids (16 KB)
  __shared__ int hist[BNODES];
  __shared__ int offs[BNODES];     // inclusive ends
  __shared__ int cur[BNODES];      // scatter cursors (mutated)

  const int b = blockIdx.x;
  const int base = b << CAPSHIFT;
  int cnt = cursor[b] - base;
  if (cnt > CAP) cnt = CAP;        // overflow handled by overflow_kernel
  const int lo = b << BSHIFT;
  const int tid = threadIdx.x;
  const int grp = tid >> 2;        // node-within-bucket this group owns
  const int ln = tid & 3;          // 32B slice within the 128B row

  for (int i = tid; i < BNODES; i += K4_THREADS) hist[i] = 0;
  __syncthreads();
  for (int i = tid; i < cnt; i += K4_THREADS) {
    int v = order[base + i];
    ids[i] = v;
    atomicAdd(&hist[v & (BNODES - 1)], 1);
  }
  __syncthreads();

  // Single-wave inclusive scan over 128 counters (lane l owns 2l, 2l+1).
  if (tid < 64) {
    int c0 = hist[2 * tid], c1 = hist[2 * tid + 1];
    int s = c0 + c1;
    int sc = s;
    #pragma unroll
    for (int off = 1; off < 64; off <<= 1) {
      int t = __shfl_up(sc, off);
      if (tid >= off) sc += t;
    }
    int bs = sc - s;                 // exclusive base for node 2*tid
    offs[2 * tid] = bs + c0;         // inclusive end of node 2*tid
    offs[2 * tid + 1] = bs + c0 + c1;
    cur[2 * tid] = bs;
    cur[2 * tid + 1] = bs + c0;
  }
  __syncthreads();

  for (int i = tid; i < cnt; i += K4_THREADS) {
    int v = ids[i];
    sorted[atomicAdd(&cur[v & (BNODES - 1)], 1)] = v;
  }
  __syncthreads();

  // Consume this group's contiguous sublist; 4-id unroll (8 loads live).
  float4 acc0 = make_float4(0.f, 0.f, 0.f, 0.f);
  float4 acc1 = make_float4(0.f, 0.f, 0.f, 0.f);
  int e_ = offs[grp];
  int i = e_ - hist[grp];
  for (; i + 3 < e_; i += 4) {
    int r0 = sorted[i] >> BSHIFT;
    int r1 = sorted[i + 1] >> BSHIFT;
    int r2 = sorted[i + 2] >> BSHIFT;
    int r3 = sorted[i + 3] >> BSHIFT;
    const float4* p0 = data + (size_t)r0 * 8 + ln * 2;
    const float4* p1 = data + (size_t)r1 * 8 + ln * 2;
    const float4* p2 = data + (size_t)r2 * 8 + ln * 2;
    const float4* p3 = data + (size_t)r3 * 8 + ln * 2;
    float4 x0 = p0[0], y0 = p0[1];
    float4 x1 = p1[0], y1 = p1[1];
    float4 x2 = p2[0], y2 = p2[1];
    float4 x3 = p3[0], y3 = p3[1];
    acc0.x += x0.x + x1.x + x2.x + x3.x;
    acc0.y += x0.y + x1.y + x2.y + x3.y;
    acc0.z += x0.z + x1.z + x2.z + x3.z;
    acc0.w += x0.w + x1.w + x2.w + x3.w;
    acc1.x += y0.x + y1.x + y2.x + y3.x;
    acc1.y += y0.y + y1.y + y2.y + y3.y;
    acc1.z += y0.z + y1.z + y2.z + y3.z;
    acc1.w += y0.w + y1.w + y2.w + y3.w;
  }
  for (; i < e_; ++i) {
    int r0 = sorted[i] >> BSHIFT;
    const float4* p0 = data + (size_t)r0 * 8 + ln * 2;
    float4 x0 = p0[0], y0 = p0[1];
    acc0.x += x0.x; acc0.y += x0.y; acc0.z += x0.z; acc0.w += x0.w;
    acc1.x += y0.x; acc1.y += y0.y; acc1.z += y0.z; acc1.w += y0.w;
  }

  int node = lo + grp;
  if (node < N) {
    float4 o0, o1;
    o0.x = acc0.x * FACTOR; o0.y = acc0.y * FACTOR;
    o0.z = acc0.z * FACTOR; o0.w = acc0.w * FACTOR;
    o1.x = acc1.x * FACTOR; o1.y = acc1.y * FACTOR;
    o1.z = acc1.z * FACTOR; o1.w = acc1.w * FACTOR;
    out[(size_t)node * 8 + ln * 2] = o0;
    out[(size_t)node * 8 + ln * 2 + 1] = o1;
  }
}

// ---------- K3: replay overflow edges (normally zero) ----------
__global__ void overflow_kernel(const float4* __restrict__ data,
                                const int2* __restrict__ ovf,
                                const int* __restrict__ ovf_count,
                                float* __restrict__ out) {
  int cnt = *ovf_count;
  for (int i = blockIdx.x * blockDim.x + threadIdx.x; i < cnt * 8;
       i += gridDim.x * blockDim.x) {
    int k = i >> 3, q = i & 7;
    int2 ed = ovf[k];
    float4 v = data[(size_t)ed.x * 8 + q];
    float* p = out + (size_t)ed.y * D + q * 4;
    unsafeAtomicAdd(p + 0, v.x * FACTOR);
    unsafeAtomicAdd(p + 1, v.y * FACTOR);
    unsafeAtomicAdd(p + 2, v.z * FACTOR);
    unsafeAtomicAdd(p + 3, v.w * FACTOR);
  }
}

// ---------- Fallback: round-1 atomic scatter ----------
__global__ void atomic_kernel(const float4* __restrict__ edge_data,
                              const int* __restrict__ edge_dst,
                              float* __restrict__ out, int E, int N) {
  int tid = blockIdx.x * blockDim.x + threadIdx.x;
  int e = tid >> 3;
  int q = tid & 7;
  if (e >= E) return;
  int dst = edge_dst[e];
  if (dst < 0 || dst >= N) return;
  float4 v = edge_data[(size_t)e * 8 + q];
  float* p = out + (size_t)dst * D + q * 4;
  unsafeAtomicAdd(p + 0, v.x * FACTOR);
  unsafeAtomicAdd(p + 1, v.y * FACTOR);
  unsafeAtomicAdd(p + 2, v.z * FACTOR);
  unsafeAtomicAdd(p + 3, v.w * FACTOR);
}

extern "C" void kernel_launch(void* const* d_in, const int* in_sizes, int n_in,
                              void* d_out, int out_size, void* d_ws, size_t ws_size,
                              hipStream_t stream) {
  const float4* edge_data = (const float4*)d_in[0];
  const int* edge_dst = (const int*)d_in[1];

  int E = in_sizes[1];
  int N = out_size / D;

  int nb = (N + BNODES - 1) >> BSHIFT;            // 782 for N=100K
  // ws layout (ints): [0..3] ovf_count+pad, [4, 4+nb) cursor,
  // [ofs_order, +nb*CAP) order, then int2 ovf[E].
  size_t ofs_order = 4 + (size_t)nb;
  ofs_order = (ofs_order + 1) & ~(size_t)1;
  size_t ofs_ovf = ofs_order + (size_t)nb * CAP;
  ofs_ovf = (ofs_ovf + 1) & ~(size_t)1;
  size_t need = (ofs_ovf + (size_t)2 * E) * sizeof(int);
  bool pack_ok = ((long long)E << BSHIFT) < (1ll << 31) &&
                 (((long long)nb << CAPSHIFT) < (1ll << 31));

  if (ws_size < need || !pack_ok) {
    float* out = (float*)d_out;
    hipMemsetAsync(d_out, 0, (size_t)out_size * sizeof(float), stream);
    int total = E * 8;
    atomic_kernel<<<(total + 255) / 256, 256, 0, stream>>>(edge_data, edge_dst, out, E, N);
    return;
  }

  int* ws = (int*)d_ws;
  int* ovf_count = ws;
  int* cursor = ws + 4;
  int* order = ws + ofs_order;
  int2* ovf = (int2*)(ws + ofs_ovf);

  init_kernel<<<(nb + 1023) / 1024, 1024, 0, stream>>>(cursor, ovf_count, nb);

  // 128 scatter blocks: per-(block,bucket) region ~ E/(128*nb)*4B ~ 64 B
  // = one cache line -> clean L2 write combining.
  int nblk = 128;
  int chunk = ((E + nblk - 1) / nblk + 3) & ~3;
  size_t lds = (size_t)2 * nb * sizeof(int);
  scatter_kernel<<<nblk, 256, lds, stream>>>(edge_dst, cursor, order, ovf,
                                             ovf_count, E, N, nb, chunk);

  gather_kernel<<<nb, K4_THREADS, 0, stream>>>(
      edge_data, order, cursor, (float4*)d_out, N);

  overflow_kernel<<<32, 256, 0, stream>>>(edge_data, ovf, ovf_count, (float*)d_out);
}